// Round 24
// baseline (72.201 us; speedup 1.0000x reference)
//
#include <hip/hip_runtime.h>
#include <cstdint>

#define BB 8
#define CC 256
#define HH 128
#define WW 128
#define HW (HH * WW)

typedef __attribute__((ext_vector_type(8))) short bf16x8;
typedef __attribute__((ext_vector_type(4))) float f32x4;

// round-to-nearest-even f32 -> bf16 (low 16 bits)
__device__ __forceinline__ uint32_t f2bf(float f) {
    uint32_t u = __float_as_uint(f);
    return (u + 0x7FFFu + ((u >> 16) & 1u)) >> 16;
}
__device__ __forceinline__ float bf2f(uint32_t u) {
    return __uint_as_float(u << 16);
}

// ---------------------------------------------------------------------------
// Kernel A: per-position channel mean & max of x -> y2 (B, H*W, 2) float2.
// Folds the B-fragment pre-pack (20 elements per block, threads 0..19).
// Bpre layout [grp][j][e] (grp = ci*7+r): padded-K im2col order; e==7 and
// grp>=14 are ZERO (kill A-side pad garbage: finite*0 = 0). Unswizzled
// blockIdx (r22's producer-side swizzle regressed).
// ---------------------------------------------------------------------------
__global__ __launch_bounds__(512) void reduce_meanmax(const float* __restrict__ x,
                                                      float* __restrict__ y2,
                                                      const float* __restrict__ w_off,
                                                      uint16_t* __restrict__ Bpre) {
    const int bh = blockIdx.x;
    const int b  = bh >> 7;
    const int h  = bh & 127;
    const int t  = threadIdx.x;

    // ---- folded prep_B: 1024 blocks x 20 = 20480 = 16*160*8 ----
    if (t < 20) {
        const int idx = bh * 20 + t;
        const int e   = idx & 7;
        const int t1  = idx >> 3;
        const int j   = t1 % 160;
        const int grp = t1 / 160;          // 0..15
        uint16_t v = 0;
        if (grp < 14 && e < 7 && j < 147) {
            const int ci = grp / 7, r = grp % 7;
            const int ch = (j < 49) ? (2 * j) : ((j < 98) ? (2 * (j - 49) + 1) : j);
            v = (uint16_t)f2bf(w_off[(size_t)ch * 98 + ci * 49 + r * 7 + e]);
        }
        Bpre[idx] = v;
    }

    const int wq = t & 31;       // float4 column: w = wq*4
    const int cg = t >> 5;       // channel group 0..15 (16 channels each)
    const float* xb = x + ((size_t)(b * CC + cg * 16) * HH + h) * WW;

    float4 s = make_float4(0.f, 0.f, 0.f, 0.f);
    float4 m = make_float4(-INFINITY, -INFINITY, -INFINITY, -INFINITY);
    #pragma unroll 4
    for (int i = 0; i < 16; ++i) {
        float4 v = ((const float4*)(xb + (size_t)i * HW))[wq];
        s.x += v.x; s.y += v.y; s.z += v.z; s.w += v.w;
        m.x = fmaxf(m.x, v.x); m.y = fmaxf(m.y, v.y);
        m.z = fmaxf(m.z, v.z); m.w = fmaxf(m.w, v.w);
    }

    __shared__ float4 ls[16][32];
    __shared__ float4 lm[16][32];
    ls[cg][wq] = s;
    lm[cg][wq] = m;
    __syncthreads();

    if (t < 32) {
        float4 S = ls[0][t];
        float4 M = lm[0][t];
        #pragma unroll
        for (int g = 1; g < 16; ++g) {
            float4 a = ls[g][t];
            float4 c = lm[g][t];
            S.x += a.x; S.y += a.y; S.z += a.z; S.w += a.w;
            M.x = fmaxf(M.x, c.x); M.y = fmaxf(M.y, c.y);
            M.z = fmaxf(M.z, c.z); M.w = fmaxf(M.w, c.w);
        }
        const float inv = 1.0f / 256.0f;
        float4 o0 = make_float4(S.x * inv, M.x, S.y * inv, M.y);
        float4 o1 = make_float4(S.z * inv, M.z, S.w * inv, M.w);
        float4* yo = (float4*)(y2 + ((size_t)b * HW + (size_t)h * WW) * 2);
        yo[2 * t]     = o0;
        yo[2 * t + 1] = o1;
    }
}

// ---------------------------------------------------------------------------
// Kernel B: gate compute + fused broadcast write, EIGHTH-ROW blocks.
// Grid = 8192 blocks (16 positions each), 128 threads = 2 waves.
// r24: clean granularity test -- per-wave work identical to r18 (acc[5],
// 20 MFMA, 8 sampling positions in 2 batches of 4), but LDS drops to
// ~6.2 KB and 128-thread blocks double resident blocks/CU, interleaving
// the per-block stage->conv->sample->write chain across ~2x more peers.
// Wave wv = nhalf (5 N-tiles); M-tile = all 16 block positions.
// Lessons kept: no min-waves hint (r3/r4/r6); no inter-block sync (r13);
// de-interleaved padded-K A-fragments (r17); batched gathers + XCD chunk
// swizzle (r18); NT fused write (r16/r19/r20/r21 variants all worse).
// ---------------------------------------------------------------------------
__global__ __launch_bounds__(128) void deform_gate(
    const float* __restrict__ y2, const uint16_t* __restrict__ Bpre,
    const float* __restrict__ b_off,
    const float* __restrict__ w_dcn, const float* __restrict__ b_dcn,
    const float* __restrict__ bn_gamma, const float* __restrict__ bn_beta,
    const float* __restrict__ bn_mean, const float* __restrict__ bn_var,
    float* __restrict__ out)
{
    // bijective XCD-chunk swizzle (8192 % 8 == 0)
    const int bid  = (blockIdx.x & 7) * 1024 + (blockIdx.x >> 3);
    const int rowg = bid >> 3;          // b*128 + h
    const int opos = (bid & 7) * 16;    // position base (16 per block)
    const int b = rowg >> 7;
    const int h = rowg & 127;
    const int t = threadIdx.x;
    const int wv = t >> 6;              // 0..1 = N-half
    const int l  = t & 63;
    const bool act = (l < 49);
    const int ls = act ? l : 0;

    __shared__ uint16_t patch2[16][24];    // de-interleaved bf16 planes, padded-K rows
    __shared__ uint16_t cv[16][168];       // conv out bf16 [pos][j]
    __shared__ float gate_blk[16];

    const float2* y2b = (const float2*)y2 + (size_t)b * HW;

    // ---- stage plane rows (mean -> 0..6, max -> 7..13; rows 14/15 + pad = 0) ----
    for (int i = t; i < 16 * 24; i += 128) {
        const int r  = i / 24;
        const int xi = i % 24;
        uint16_t v = 0;
        if (r < 14 && xi < 22) {
            const int ci = (r >= 7) ? 1 : 0;
            const int rr = r - 7 * ci;
            const int xx = opos + xi - 3;
            const int yy = h + rr - 3;
            if (yy >= 0 && yy < HH && xx >= 0 && xx < WW) {
                float2 g2 = y2b[yy * WW + xx];
                v = (uint16_t)(ci ? f2bf(g2.y) : f2bf(g2.x));
            }
        }
        patch2[r][xi] = v;
    }

    // per-lane (tap) sampling constants
    const float b_dy = b_off[2 * ls];
    const float b_dx = b_off[2 * ls + 1];
    const float b_m  = b_off[98 + ls];
    const float wd0 = w_dcn[ls];
    const float wd1 = w_dcn[49 + ls];
    const int kr = ls / 7;
    const int kc = ls % 7;
    const float bscale = bn_gamma[0] * rsqrtf(bn_var[0] + 1e-5f);
    const float gB = (b_dcn[0] - bn_mean[0]) * bscale + bn_beta[0];

    __syncthreads();

    // ---- MFMA conv: 16 positions x 80 channels (wave wv = N-half) ----
    const int m = l & 15;
    const int g = l >> 4;
    const uint32_t* p32 = (const uint32_t*)&patch2[0][0];

    f32x4 acc[5];
    #pragma unroll
    for (int nn = 0; nn < 5; ++nn) acc[nn] = (f32x4){0.f, 0.f, 0.f, 0.f};

    #pragma unroll
    for (int kt = 0; kt < 4; ++kt) {
        const int grp = kt * 4 + g;
        const int W   = grp * 24 + m;              // u16 index of fragment start
        const uint32_t sh8 = (W & 1) ? 16u : 0u;
        const uint32_t* dp = p32 + (W >> 1);
        const uint32_t d0 = dp[0], d1 = dp[1], d2 = dp[2], d3 = dp[3], d4 = dp[4];
        union { uint32_t u[4]; bf16x8 v; } af;
        af.u[0] = (uint32_t)(((((uint64_t)d1) << 32) | d0) >> sh8);
        af.u[1] = (uint32_t)(((((uint64_t)d2) << 32) | d1) >> sh8);
        af.u[2] = (uint32_t)(((((uint64_t)d3) << 32) | d2) >> sh8);
        af.u[3] = (uint32_t)(((((uint64_t)d4) << 32) | d3) >> sh8);
        #pragma unroll
        for (int nn = 0; nn < 5; ++nn) {
            const int j = (wv * 5 + nn) * 16 + m;
            const bf16x8 bfr = *(const bf16x8*)(Bpre + ((grp * 160 + j) << 3));
            acc[nn] = __builtin_amdgcn_mfma_f32_16x16x32_bf16(af.v, bfr, acc[nn], 0, 0, 0);
        }
    }

    #pragma unroll
    for (int nn = 0; nn < 5; ++nn) {
        #pragma unroll
        for (int q = 0; q < 4; ++q) {
            cv[g * 4 + q][(wv * 5 + nn) * 16 + m] = (uint16_t)f2bf(acc[nn][q]);
        }
    }
    __syncthreads();

    // ---- sampling: wave wv owns positions [8*wv, 8*wv+8); 2 batches of 4 ----
    const uint16_t* cvp = &cv[0][0];
    #pragma unroll 1
    for (int hb = 0; hb < 2; ++hb) {
        const int p0 = wv * 8 + hb * 4;

        float mkv[4], w00[4], w01[4], w10[4], w11[4];
        float2 g00[4], g01[4], g10[4], g11[4];

        #pragma unroll
        for (int pi = 0; pi < 4; ++pi) {
            const int pp = p0 + pi;
            const int cbase = pp * 168;

            const float dyv = bf2f(cvp[cbase + ls])      + b_dy;
            const float dxv = bf2f(cvp[cbase + 49 + ls]) + b_dx;
            const float mv  = bf2f(cvp[cbase + 98 + ls]) + b_m;
            mkv[pi] = 1.0f / (1.0f + __expf(-mv));

            const float fy = (float)(h + kr - 3) + dyv;
            const float fx = (float)(opos + pp + kc - 3) + dxv;
            const float fly = floorf(fy), flx = floorf(fx);
            const int iy0 = (int)fly, ix0 = (int)flx;
            const int iy1 = iy0 + 1,  ix1 = ix0 + 1;
            const float wy1 = fy - fly, wy0 = 1.0f - wy1;
            const float wx1 = fx - flx, wx0 = 1.0f - wx1;

            const float vy0 = (iy0 >= 0 && iy0 < HH) ? 1.0f : 0.0f;
            const float vy1 = (iy1 >= 0 && iy1 < HH) ? 1.0f : 0.0f;
            const float vx0 = (ix0 >= 0 && ix0 < WW) ? 1.0f : 0.0f;
            const float vx1 = (ix1 >= 0 && ix1 < WW) ? 1.0f : 0.0f;

            const int cy0 = min(max(iy0, 0), HH - 1) * WW;
            const int cy1 = min(max(iy1, 0), HH - 1) * WW;
            const int cx0 = min(max(ix0, 0), WW - 1);
            const int cx1 = min(max(ix1, 0), WW - 1);

            w00[pi] = wy0 * wx0 * vy0 * vx0;
            w01[pi] = wy0 * wx1 * vy0 * vx1;
            w10[pi] = wy1 * wx0 * vy1 * vx0;
            w11[pi] = wy1 * wx1 * vy1 * vx1;

            g00[pi] = y2b[cy0 + cx0];
            g01[pi] = y2b[cy0 + cx1];
            g10[pi] = y2b[cy1 + cx0];
            g11[pi] = y2b[cy1 + cx1];
        }

        float tv[4];
        #pragma unroll
        for (int pi = 0; pi < 4; ++pi) {
            const float v0s = g00[pi].x * w00[pi] + g01[pi].x * w01[pi]
                            + g10[pi].x * w10[pi] + g11[pi].x * w11[pi];
            const float v1s = g00[pi].y * w00[pi] + g01[pi].y * w01[pi]
                            + g10[pi].y * w10[pi] + g11[pi].y * w11[pi];
            float tval = mkv[pi] * fmaf(v0s, wd0, v1s * wd1);
            tv[pi] = act ? tval : 0.0f;
        }

        // 4 interleaved 6-step reductions
        #pragma unroll
        for (int off = 1; off < 64; off <<= 1) {
            #pragma unroll
            for (int pi = 0; pi < 4; ++pi)
                tv[pi] += __shfl_xor(tv[pi], off);
        }

        if (l == 0) {
            #pragma unroll
            for (int pi = 0; pi < 4; ++pi) {
                const float o = tv[pi] * bscale + gB;
                gate_blk[p0 + pi] = 1.0f / (1.0f + __expf(-o));
            }
        }
    }

    __syncthreads();

    // ---- fused broadcast write: out[b, :, h, opos:opos+16] (16 KB/block) ----
    const size_t ob = (size_t)b * CC * HW + (size_t)h * WW + opos;
    const f32x4* gb4 = (const f32x4*)gate_blk;
    #pragma unroll
    for (int it = 0; it < 8; ++it) {
        const int idx = it * 128 + t;      // 0..1023
        const int c   = idx >> 2;          // channel
        const int q4  = idx & 3;           // f32x4 slice within the 16 floats
        __builtin_nontemporal_store(gb4[q4], (f32x4*)(out + ob + (size_t)c * HW) + q4);
    }
}

extern "C" void kernel_launch(void* const* d_in, const int* in_sizes, int n_in,
                              void* d_out, int out_size, void* d_ws, size_t ws_size,
                              hipStream_t stream) {
    const float* x        = (const float*)d_in[0];
    const float* w_off    = (const float*)d_in[1];
    const float* b_off    = (const float*)d_in[2];
    const float* w_dcn    = (const float*)d_in[3];
    const float* b_dcn    = (const float*)d_in[4];
    const float* bn_gamma = (const float*)d_in[5];
    const float* bn_beta  = (const float*)d_in[6];
    const float* bn_mean  = (const float*)d_in[7];
    const float* bn_var   = (const float*)d_in[8];
    float* out = (float*)d_out;

    float*    y2   = (float*)d_ws;                              // 1 MiB
    uint16_t* Bpre = (uint16_t*)((char*)d_ws + (1 << 20));      // 40 KiB

    reduce_meanmax<<<BB * HH, 512, 0, stream>>>(x, y2, w_off, Bpre);
    deform_gate<<<8 * BB * HH, 128, 0, stream>>>(y2, Bpre, b_off, w_dcn, b_dcn,
                                                 bn_gamma, bn_beta, bn_mean, bn_var,
                                                 out);
}

// Round 25
// 67.560 us; speedup vs baseline: 1.0687x; 1.0687x over previous
//
#include <hip/hip_runtime.h>
#include <cstdint>

#define BB 8
#define CC 256
#define HH 128
#define WW 128
#define HW (HH * WW)

typedef __attribute__((ext_vector_type(8))) short bf16x8;
typedef __attribute__((ext_vector_type(4))) float f32x4;

// round-to-nearest-even f32 -> bf16 (low 16 bits)
__device__ __forceinline__ uint32_t f2bf(float f) {
    uint32_t u = __float_as_uint(f);
    return (u + 0x7FFFu + ((u >> 16) & 1u)) >> 16;
}
__device__ __forceinline__ float bf2f(uint32_t u) {
    return __uint_as_float(u << 16);
}

// ---------------------------------------------------------------------------
// Kernel A: per-position channel mean & max of x -> y2 (B, H*W, 2) float2.
// Folds the B-fragment pre-pack (20 elements per block, threads 0..19).
// Bpre layout [grp][j][e] (grp = ci*7+r): padded-K im2col order; e==7 and
// grp>=14 are ZERO (kill A-side pad garbage: finite*0 = 0).
// ---------------------------------------------------------------------------
__global__ __launch_bounds__(512) void reduce_meanmax(const float* __restrict__ x,
                                                      float* __restrict__ y2,
                                                      const float* __restrict__ w_off,
                                                      uint16_t* __restrict__ Bpre) {
    const int bh = blockIdx.x;
    const int b  = bh >> 7;
    const int h  = bh & 127;
    const int t  = threadIdx.x;

    // ---- folded prep_B: 1024 blocks x 20 = 20480 = 16*160*8 ----
    if (t < 20) {
        const int idx = bh * 20 + t;
        const int e   = idx & 7;
        const int t1  = idx >> 3;
        const int j   = t1 % 160;
        const int grp = t1 / 160;          // 0..15
        uint16_t v = 0;
        if (grp < 14 && e < 7 && j < 147) {
            const int ci = grp / 7, r = grp % 7;
            const int ch = (j < 49) ? (2 * j) : ((j < 98) ? (2 * (j - 49) + 1) : j);
            v = (uint16_t)f2bf(w_off[(size_t)ch * 98 + ci * 49 + r * 7 + e]);
        }
        Bpre[idx] = v;
    }

    const int wq = t & 31;       // float4 column: w = wq*4
    const int cg = t >> 5;       // channel group 0..15 (16 channels each)
    const float* xb = x + ((size_t)(b * CC + cg * 16) * HH + h) * WW;

    float4 s = make_float4(0.f, 0.f, 0.f, 0.f);
    float4 m = make_float4(-INFINITY, -INFINITY, -INFINITY, -INFINITY);
    #pragma unroll 4
    for (int i = 0; i < 16; ++i) {
        float4 v = ((const float4*)(xb + (size_t)i * HW))[wq];
        s.x += v.x; s.y += v.y; s.z += v.z; s.w += v.w;
        m.x = fmaxf(m.x, v.x); m.y = fmaxf(m.y, v.y);
        m.z = fmaxf(m.z, v.z); m.w = fmaxf(m.w, v.w);
    }

    __shared__ float4 ls[16][32];
    __shared__ float4 lm[16][32];
    ls[cg][wq] = s;
    lm[cg][wq] = m;
    __syncthreads();

    if (t < 32) {
        float4 S = ls[0][t];
        float4 M = lm[0][t];
        #pragma unroll
        for (int g = 1; g < 16; ++g) {
            float4 a = ls[g][t];
            float4 c = lm[g][t];
            S.x += a.x; S.y += a.y; S.z += a.z; S.w += a.w;
            M.x = fmaxf(M.x, c.x); M.y = fmaxf(M.y, c.y);
            M.z = fmaxf(M.z, c.z); M.w = fmaxf(M.w, c.w);
        }
        const float inv = 1.0f / 256.0f;
        float4 o0 = make_float4(S.x * inv, M.x, S.y * inv, M.y);
        float4 o1 = make_float4(S.z * inv, M.z, S.w * inv, M.w);
        float4* yo = (float4*)(y2 + ((size_t)b * HW + (size_t)h * WW) * 2);
        yo[2 * t]     = o0;
        yo[2 * t + 1] = o1;
    }
}

// ---------------------------------------------------------------------------
// Kernel B: gate compute + fused broadcast write. Grid = 4096 blocks (one per
// quarter-row = 32 positions), 256 threads = 4 waves. (Champion: r18,
// reproduced 67.6us in r23.)
// (1) XCD-chunk bid swizzle (consumer side only); (2) sampling in 2 batches
// of 4 positions: all 16 gathers issued before consumption, 4 interleaved
// shfl-reduce chains; (3) de-interleaved padded-K A-fragments (5 dword LDS
// reads + funnel shifts per fragment); (4) NT quarter-row fused write.
// Lessons: no min-waves hint (r3/r4/r6 spills); no inter-block sync (r13);
// quarter-row grain optimal (r21 full-row / r24 eighth-row both worse);
// fused write beats split (r20 +24us); plain stores neutral (r16);
// intra-block write pipelining regressed (r19); producer swizzle regressed
// (r22).
// ---------------------------------------------------------------------------
__global__ __launch_bounds__(256) void deform_gate(
    const float* __restrict__ y2, const uint16_t* __restrict__ Bpre,
    const float* __restrict__ b_off,
    const float* __restrict__ w_dcn, const float* __restrict__ b_dcn,
    const float* __restrict__ bn_gamma, const float* __restrict__ bn_beta,
    const float* __restrict__ bn_mean, const float* __restrict__ bn_var,
    float* __restrict__ out)
{
    // bijective XCD-chunk swizzle (4096 % 8 == 0)
    const int bid  = (blockIdx.x & 7) * 512 + (blockIdx.x >> 3);
    const int rowg = bid >> 2;          // b*128 + h
    const int qpos = (bid & 3) * 32;
    const int b = rowg >> 7;
    const int h = rowg & 127;
    const int t = threadIdx.x;
    const int wv = t >> 6;
    const int l  = t & 63;
    const int mhalf = wv >> 1;
    const int nhalf = wv & 1;
    const bool act = (l < 49);
    const int ls = act ? l : 0;

    __shared__ uint16_t patch2[16][48];    // de-interleaved bf16 planes, padded-K rows
    __shared__ uint16_t cv[2][16][168];    // conv out bf16 [mhalf][pos][j]
    __shared__ float gate_blk[32];

    const float2* y2b = (const float2*)y2 + (size_t)b * HW;

    // ---- stage plane rows: mean -> patch2[r], max -> patch2[7+r] ----
    for (int i = t; i < 7 * 40; i += 256) {
        const int r  = i / 40;
        const int xi = i % 40;
        const int xx = qpos + xi - 3;
        const int yy = h + r - 3;
        uint32_t mn = 0, mx = 0;
        if (yy >= 0 && yy < HH && xx >= 0 && xx < WW) {
            float2 g2 = y2b[yy * WW + xx];
            mn = f2bf(g2.x);
            mx = f2bf(g2.y);
        }
        patch2[r][xi]     = (uint16_t)mn;
        patch2[7 + r][xi] = (uint16_t)mx;
    }
    // zero pad rows 14,15
    for (int i = t; i < 2 * 48; i += 256)
        patch2[14 + (i / 48)][i % 48] = 0;

    // per-lane (tap) sampling constants
    const float b_dy = b_off[2 * ls];
    const float b_dx = b_off[2 * ls + 1];
    const float b_m  = b_off[98 + ls];
    const float wd0 = w_dcn[ls];
    const float wd1 = w_dcn[49 + ls];
    const int kr = ls / 7;
    const int kc = ls % 7;
    const float bscale = bn_gamma[0] * rsqrtf(bn_var[0] + 1e-5f);
    const float gB = (b_dcn[0] - bn_mean[0]) * bscale + bn_beta[0];

    __syncthreads();

    // ---- MFMA conv: 16 positions (mhalf) x 80 channels (nhalf) ----
    const int m = l & 15;
    const int g = l >> 4;
    const int plocal = mhalf * 16 + m;
    const uint32_t* p32 = (const uint32_t*)&patch2[0][0];

    f32x4 acc[5];
    #pragma unroll
    for (int nn = 0; nn < 5; ++nn) acc[nn] = (f32x4){0.f, 0.f, 0.f, 0.f};

    #pragma unroll
    for (int kt = 0; kt < 4; ++kt) {
        const int grp = kt * 4 + g;
        const int W   = grp * 48 + plocal;         // u16 index of fragment start
        const uint32_t sh8 = (W & 1) ? 16u : 0u;
        const uint32_t* dp = p32 + (W >> 1);
        const uint32_t d0 = dp[0], d1 = dp[1], d2 = dp[2], d3 = dp[3], d4 = dp[4];
        union { uint32_t u[4]; bf16x8 v; } af;
        af.u[0] = (uint32_t)(((((uint64_t)d1) << 32) | d0) >> sh8);
        af.u[1] = (uint32_t)(((((uint64_t)d2) << 32) | d1) >> sh8);
        af.u[2] = (uint32_t)(((((uint64_t)d3) << 32) | d2) >> sh8);
        af.u[3] = (uint32_t)(((((uint64_t)d4) << 32) | d3) >> sh8);
        #pragma unroll
        for (int nn = 0; nn < 5; ++nn) {
            const int j = (nhalf * 5 + nn) * 16 + m;
            const bf16x8 bfr = *(const bf16x8*)(Bpre + ((grp * 160 + j) << 3));
            acc[nn] = __builtin_amdgcn_mfma_f32_16x16x32_bf16(af.v, bfr, acc[nn], 0, 0, 0);
        }
    }

    #pragma unroll
    for (int nn = 0; nn < 5; ++nn) {
        #pragma unroll
        for (int q = 0; q < 4; ++q) {
            cv[mhalf][g * 4 + q][(nhalf * 5 + nn) * 16 + m] = (uint16_t)f2bf(acc[nn][q]);
        }
    }
    __syncthreads();

    // ---- sampling: wave wv owns positions [8*wv, 8*wv+8); 2 batches of 4 ----
    const uint16_t* cvp = &cv[0][0][0];
    #pragma unroll 1
    for (int hb = 0; hb < 2; ++hb) {
        const int p0 = wv * 8 + hb * 4;

        float mkv[4], w00[4], w01[4], w10[4], w11[4];
        float2 g00[4], g01[4], g10[4], g11[4];

        #pragma unroll
        for (int pi = 0; pi < 4; ++pi) {
            const int pp = p0 + pi;
            const int cbase = pp * 168;

            const float dyv = bf2f(cvp[cbase + ls])      + b_dy;
            const float dxv = bf2f(cvp[cbase + 49 + ls]) + b_dx;
            const float mv  = bf2f(cvp[cbase + 98 + ls]) + b_m;
            mkv[pi] = 1.0f / (1.0f + __expf(-mv));

            const float fy = (float)(h + kr - 3) + dyv;
            const float fx = (float)(qpos + pp + kc - 3) + dxv;
            const float fly = floorf(fy), flx = floorf(fx);
            const int iy0 = (int)fly, ix0 = (int)flx;
            const int iy1 = iy0 + 1,  ix1 = ix0 + 1;
            const float wy1 = fy - fly, wy0 = 1.0f - wy1;
            const float wx1 = fx - flx, wx0 = 1.0f - wx1;

            const float vy0 = (iy0 >= 0 && iy0 < HH) ? 1.0f : 0.0f;
            const float vy1 = (iy1 >= 0 && iy1 < HH) ? 1.0f : 0.0f;
            const float vx0 = (ix0 >= 0 && ix0 < WW) ? 1.0f : 0.0f;
            const float vx1 = (ix1 >= 0 && ix1 < WW) ? 1.0f : 0.0f;

            const int cy0 = min(max(iy0, 0), HH - 1) * WW;
            const int cy1 = min(max(iy1, 0), HH - 1) * WW;
            const int cx0 = min(max(ix0, 0), WW - 1);
            const int cx1 = min(max(ix1, 0), WW - 1);

            w00[pi] = wy0 * wx0 * vy0 * vx0;
            w01[pi] = wy0 * wx1 * vy0 * vx1;
            w10[pi] = wy1 * wx0 * vy1 * vx0;
            w11[pi] = wy1 * wx1 * vy1 * vx1;

            g00[pi] = y2b[cy0 + cx0];
            g01[pi] = y2b[cy0 + cx1];
            g10[pi] = y2b[cy1 + cx0];
            g11[pi] = y2b[cy1 + cx1];
        }

        float tv[4];
        #pragma unroll
        for (int pi = 0; pi < 4; ++pi) {
            const float v0s = g00[pi].x * w00[pi] + g01[pi].x * w01[pi]
                            + g10[pi].x * w10[pi] + g11[pi].x * w11[pi];
            const float v1s = g00[pi].y * w00[pi] + g01[pi].y * w01[pi]
                            + g10[pi].y * w10[pi] + g11[pi].y * w11[pi];
            float tval = mkv[pi] * fmaf(v0s, wd0, v1s * wd1);
            tv[pi] = act ? tval : 0.0f;
        }

        // 4 interleaved 6-step reductions
        #pragma unroll
        for (int off = 1; off < 64; off <<= 1) {
            #pragma unroll
            for (int pi = 0; pi < 4; ++pi)
                tv[pi] += __shfl_xor(tv[pi], off);
        }

        if (l == 0) {
            #pragma unroll
            for (int pi = 0; pi < 4; ++pi) {
                const float o = tv[pi] * bscale + gB;
                gate_blk[p0 + pi] = 1.0f / (1.0f + __expf(-o));
            }
        }
    }

    __syncthreads();

    // ---- fused broadcast write: out[b, :, h, qpos:qpos+32] (32 KB/block) ----
    const size_t ob = (size_t)b * CC * HW + (size_t)h * WW + qpos;
    const f32x4* gb4 = (const f32x4*)gate_blk;
    #pragma unroll
    for (int it = 0; it < 8; ++it) {
        const int idx = it * 256 + t;
        const int c   = idx >> 3;
        const int q4  = idx & 7;
        __builtin_nontemporal_store(gb4[q4], (f32x4*)(out + ob + (size_t)c * HW) + q4);
    }
}

extern "C" void kernel_launch(void* const* d_in, const int* in_sizes, int n_in,
                              void* d_out, int out_size, void* d_ws, size_t ws_size,
                              hipStream_t stream) {
    const float* x        = (const float*)d_in[0];
    const float* w_off    = (const float*)d_in[1];
    const float* b_off    = (const float*)d_in[2];
    const float* w_dcn    = (const float*)d_in[3];
    const float* b_dcn    = (const float*)d_in[4];
    const float* bn_gamma = (const float*)d_in[5];
    const float* bn_beta  = (const float*)d_in[6];
    const float* bn_mean  = (const float*)d_in[7];
    const float* bn_var   = (const float*)d_in[8];
    float* out = (float*)d_out;

    float*    y2   = (float*)d_ws;                              // 1 MiB
    uint16_t* Bpre = (uint16_t*)((char*)d_ws + (1 << 20));      // 40 KiB

    reduce_meanmax<<<BB * HH, 512, 0, stream>>>(x, y2, w_off, Bpre);
    deform_gate<<<4 * BB * HH, 256, 0, stream>>>(y2, Bpre, b_off, w_dcn, b_dcn,
                                                 bn_gamma, bn_beta, bn_mean, bn_var,
                                                 out);
}